// Round 7
// baseline (139.497 us; speedup 1.0000x reference)
//
#include <hip/hip_runtime.h>
#include <math.h>

#define NS 2048
#define NT 2048
#define NATOMS 128

typedef __attribute__((ext_vector_type(8))) short bf16x8;
typedef __attribute__((ext_vector_type(4))) float f32x4;

static __device__ __forceinline__ unsigned short f2bf(float f) {
    unsigned int u = __float_as_uint(f);
    unsigned int r = (u + 0x7fffu + ((u >> 16) & 1u)) >> 16;  // RNE
    return (unsigned short)r;
}
static __device__ __forceinline__ float bf2f(unsigned short h) {
    return __uint_as_float(((unsigned int)h) << 16);
}

// ---------------- Stage A: center + hi/lo bf16 split + squared norms ----------------
__global__ __launch_bounds__(64) void center_bf16_kernel(
    const float* __restrict__ X, unsigned short* __restrict__ Hi,
    unsigned short* __restrict__ Lo, float* __restrict__ norms)
{
    const int s = blockIdx.x;
    const int lane = threadIdx.x;  // 64 lanes, 2 atoms each
    const float* xs = X + (size_t)s * (NATOMS * 3);
    float x0 = xs[lane * 3 + 0];
    float y0 = xs[lane * 3 + 1];
    float z0 = xs[lane * 3 + 2];
    float x1 = xs[(lane + 64) * 3 + 0];
    float y1 = xs[(lane + 64) * 3 + 1];
    float z1 = xs[(lane + 64) * 3 + 2];
    float sx = x0 + x1, sy = y0 + y1, sz = z0 + z1;
#pragma unroll
    for (int off = 32; off > 0; off >>= 1) {
        sx += __shfl_xor(sx, off);
        sy += __shfl_xor(sy, off);
        sz += __shfl_xor(sz, off);
    }
    const float inv_n = 1.0f / (float)NATOMS;
    const float mx = sx * inv_n, my = sy * inv_n, mz = sz * inv_n;
    x0 -= mx; y0 -= my; z0 -= mz;
    x1 -= mx; y1 -= my; z1 -= mz;

    const size_t base = (size_t)s * 384;   // [s][3][128] bf16
    const float v[3][2] = {{x0, x1}, {y0, y1}, {z0, z1}};
#pragma unroll
    for (int c = 0; c < 3; ++c)
#pragma unroll
        for (int h = 0; h < 2; ++h) {
            const unsigned short hb = f2bf(v[c][h]);
            const unsigned short lb = f2bf(v[c][h] - bf2f(hb));
            Hi[base + c * 128 + h * 64 + lane] = hb;
            Lo[base + c * 128 + h * 64 + lane] = lb;
        }

    float nsq = x0 * x0 + y0 * y0 + z0 * z0 + x1 * x1 + y1 * y1 + z1 * z1;
#pragma unroll
    for (int off = 32; off > 0; off >>= 1) nsq += __shfl_xor(nsq, off);
    if (lane == 0) norms[s] = nsq;
}

// ---------------- Stage B: MFMA covariance + per-lane scalar power iteration ----------------
// Trajectory is bit-identical to Round 6: each matvec component is
// mul + 3 contracted fma in column order (pk_fma per element == v_fma_f32).
__global__ __launch_bounds__(256, 7) void pair_mfma_kernel(
    const unsigned short* __restrict__ Ahi, const unsigned short* __restrict__ Alo,
    const unsigned short* __restrict__ Bhi, const unsigned short* __restrict__ Blo,
    const float* __restrict__ norm_s, const float* __restrict__ norm_t,
    float* __restrict__ out)
{
    const int tid = threadIdx.x;
    const int wave = tid >> 6;
    const int lane = tid & 63;
    const int nrow = lane & 15;   // A m-row / B n-col / C col
    const int kgrp = lane >> 4;   // k-octet selector
    const int sBase = blockIdx.x * 16;
    const int tBase = blockIdx.y * 64 + wave * 16;

    const size_t aOff = (size_t)(sBase + nrow) * 384 + kgrp * 8;
    const size_t bOff = (size_t)(tBase + nrow) * 384 + kgrp * 8;

    f32x4 acc[3][3];
#pragma unroll
    for (int i = 0; i < 3; ++i)
#pragma unroll
        for (int j = 0; j < 3; ++j) acc[i][j] = (f32x4){0.f, 0.f, 0.f, 0.f};

#pragma unroll
    for (int ks = 0; ks < 4; ++ks) {
        bf16x8 ah[3], al[3], bh[3], bl[3];
#pragma unroll
        for (int c = 0; c < 3; ++c) {
            ah[c] = *reinterpret_cast<const bf16x8*>(Ahi + aOff + c * 128 + ks * 32);
            al[c] = *reinterpret_cast<const bf16x8*>(Alo + aOff + c * 128 + ks * 32);
            bh[c] = *reinterpret_cast<const bf16x8*>(Bhi + bOff + c * 128 + ks * 32);
            bl[c] = *reinterpret_cast<const bf16x8*>(Blo + bOff + c * 128 + ks * 32);
        }
#pragma unroll
        for (int i = 0; i < 3; ++i)
#pragma unroll
            for (int j = 0; j < 3; ++j)
                acc[i][j] = __builtin_amdgcn_mfma_f32_16x16x32_bf16(
                    ah[i], bh[j], acc[i][j], 0, 0, 0);
#pragma unroll
        for (int i = 0; i < 3; ++i)
#pragma unroll
            for (int j = 0; j < 3; ++j)
                acc[i][j] = __builtin_amdgcn_mfma_f32_16x16x32_bf16(
                    ah[i], bl[j], acc[i][j], 0, 0, 0);
#pragma unroll
        for (int i = 0; i < 3; ++i)
#pragma unroll
            for (int j = 0; j < 3; ++j)
                acc[i][j] = __builtin_amdgcn_mfma_f32_16x16x32_bf16(
                    al[i], bh[j], acc[i][j], 0, 0, 0);
    }

    // ---- Per-lane: shifted F (10 unique values per pair), 50 matvecs ----
    float D0[4], D1[4], D2[4], D3[4];            // diagonal + fro shift
    float E01[4], E02[4], E03[4], E12[4], E13[4], E23[4];
    float FRO[4];
    float q0[4], q1[4], q2[4], q3[4];
#pragma unroll
    for (int u = 0; u < 4; ++u) {
        const float Sxx = acc[0][0][u], Sxy = acc[0][1][u], Sxz = acc[0][2][u];
        const float Syx = acc[1][0][u], Syy = acc[1][1][u], Syz = acc[1][2][u];
        const float Szx = acc[2][0][u], Szy = acc[2][1][u], Szz = acc[2][2][u];
        const float F00 =  Sxx + Syy + Szz;
        const float F11 =  Sxx - Syy - Szz;
        const float F22 = -Sxx + Syy - Szz;
        const float F33 = -Sxx - Syy + Szz;
        const float F01 = Syz - Szy;
        const float F02 = Szx - Sxz;
        const float F03 = Sxy - Syx;
        const float F12 = Sxy + Syx;
        const float F13 = Sxz + Szx;
        const float F23 = Syz + Szy;
        const float fro = sqrtf(F00 * F00 + F11 * F11 + F22 * F22 + F33 * F33 +
                                2.0f * (F01 * F01 + F02 * F02 + F03 * F03 +
                                        F12 * F12 + F13 * F13 + F23 * F23));
        FRO[u] = fro;
        D0[u] = F00 + fro;
        D1[u] = F11 + fro;
        D2[u] = F22 + fro;
        D3[u] = F33 + fro;
        E01[u] = F01; E02[u] = F02; E03[u] = F03;
        E12[u] = F12; E13[u] = F13; E23[u] = F23;
        q0[u] = 0.5f; q1[u] = 0.5f; q2[u] = 0.5f; q3[u] = 0.5f;
    }

    // 50 matvecs, normalize after every 5th. Column order 0,1,2,3 per
    // component: mul then 3 fma — identical rounding to R6's packed chain.
    for (int blk = 0; blk < 10; ++blk) {
#pragma unroll
        for (int k = 0; k < 5; ++k) {
#pragma unroll
            for (int u = 0; u < 4; ++u) {
                const float w0 = fmaf(E03[u], q3[u], fmaf(E02[u], q2[u],
                                 fmaf(E01[u], q1[u], D0[u] * q0[u])));
                const float w1 = fmaf(E13[u], q3[u], fmaf(E12[u], q2[u],
                                 fmaf(D1[u], q1[u], E01[u] * q0[u])));
                const float w2 = fmaf(E23[u], q3[u], fmaf(D2[u], q2[u],
                                 fmaf(E12[u], q1[u], E02[u] * q0[u])));
                const float w3 = fmaf(D3[u], q3[u], fmaf(E23[u], q2[u],
                                 fmaf(E13[u], q1[u], E03[u] * q0[u])));
                q0[u] = w0; q1[u] = w1; q2[u] = w2; q3[u] = w3;
            }
        }
#pragma unroll
        for (int u = 0; u < 4; ++u) {
            const float a0 = q0[u], a1 = q1[u], a2 = q2[u], a3 = q3[u];
            const float nn = a0 * a0 + a1 * a1 + a2 * a2 + a3 * a3;
            const float sc = __builtin_amdgcn_rsqf(nn);
            q0[u] = a0 * sc; q1[u] = a1 * sc;
            q2[u] = a2 * sc; q3[u] = a3 * sc;
        }
    }

    const float inv_na = 1.0f / (128.0f + 1e-5f);
    const float Gb = norm_t[tBase + nrow];
#pragma unroll
    for (int u = 0; u < 4; ++u) {
        const int srow = sBase + kgrp * 4 + u;
        const float Ga = norm_s[srow];
        const float a0 = q0[u], a1 = q1[u], a2 = q2[u], a3 = q3[u];
        // Rayleigh: (q^T F_shift q)/(q^T q) - fro  (R6-identical expressions)
        const float m0 = D0[u] * a0 + E01[u] * a1 + E02[u] * a2 + E03[u] * a3;
        const float m1 = E01[u] * a0 + D1[u] * a1 + E12[u] * a2 + E13[u] * a3;
        const float m2 = E02[u] * a0 + E12[u] * a1 + D2[u] * a2 + E23[u] * a3;
        const float m3 = E03[u] * a0 + E13[u] * a1 + E23[u] * a2 + D3[u] * a3;
        const float num = a0 * m0 + a1 * m1 + a2 * m2 + a3 * m3;
        const float den = a0 * a0 + a1 * a1 + a2 * a2 + a3 * a3;
        const float eig = num * __builtin_amdgcn_rcpf(den) - FRO[u];
        float sq = (Ga + Gb - 2.0f * eig) * inv_na;
        out[(size_t)srow * NT + tBase + nrow] = sqrtf(fmaxf(sq, 0.0f));
    }
}

extern "C" void kernel_launch(void* const* d_in, const int* in_sizes, int n_in,
                              void* d_out, int out_size, void* d_ws, size_t ws_size,
                              hipStream_t stream) {
    const float* Xm = (const float*)d_in[0];
    const float* Xt = (const float*)d_in[1];
    float* out = (float*)d_out;

    unsigned short* ws16 = (unsigned short*)d_ws;
    unsigned short* Ahi = ws16;
    unsigned short* Alo = Ahi + (size_t)NS * 384;
    unsigned short* Bhi = Alo + (size_t)NS * 384;
    unsigned short* Blo = Bhi + (size_t)NT * 384;
    float* norm_m = (float*)(Blo + (size_t)NT * 384);
    float* norm_t = norm_m + NS;

    center_bf16_kernel<<<NS, 64, 0, stream>>>(Xm, Ahi, Alo, norm_m);
    center_bf16_kernel<<<NT, 64, 0, stream>>>(Xt, Bhi, Blo, norm_t);

    dim3 grid(NS / 16, NT / 64);
    pair_mfma_kernel<<<grid, 256, 0, stream>>>(Ahi, Alo, Bhi, Blo,
                                               norm_m, norm_t, out);
}